// Round 6
// baseline (207.796 us; speedup 1.0000x reference)
//
#include <hip/hip_runtime.h>
#include <math.h>

// HarmonicCQT via f16 MFMA: out[b,t,k] = |sum_n xpad[t*512+n] * (kr[k,n]+i*ki[k,n])|
//
// Path A (ws >= ~11.69MB), 3 dispatches:
//   1. prep_fused : zero acc + fp32 audio -> padded f16 xp + COALESCED
//                   B-fragment pack (16B stores, x4096 pre-scale)
//   2. cqt_mfma4  : per-wave WG, 64-frame x 32-bin tile, slab=512 split-K,
//                   ping-pong register double-buffer, 16 MFMAs/chunk,
//                   fire-and-forget fp32 atomics (guarded t<689, bin<168)
//   3. cqt_mag_final : sqrt(re^2+im^2)
// Path B (ws >= ~7.7MB): round-3 LDS-staging MFMA kernel (verified, ~224us).
// Path C: verified fp32 kernel (~370us).
//
// MFMA 16x16x32 layouts (verified rounds 3/4/5, absmax 4.9e-4):
//   A[m=lane&15][k=(lane>>4)*8+j], B[k=(lane>>4)*8+j][n=lane&15],
//   C/D: col=lane&15, row=(lane>>4)*4+reg.
// bp layout per chunk (32 K-cols, 32 bins): 4096B = 4 regions x 1KB:
//   [sg0 re][sg0 im][sg1 re][sg1 im]; within a region lane l's fragment at
//   halfs [l*8, l*8+8) == B[k=(l>>4)*8+j][n=l&15]  (verified mapping).

namespace {
constexpr int kSR    = 22050;
constexpr int kHop   = 512;
constexpr int kBins  = 168;
constexpr int kT     = 689;
constexpr int kB     = 4;
constexpr int kS     = 352768;
constexpr float kKScale    = 4096.0f;
constexpr float kKScaleInv = 1.0f / 4096.0f;
constexpr int kMaxJobs = 96;
// path A accumulator: unpadded [b][689][168][2] f32
constexpr int kAccA = kB * kT * kBins * 2;       // 925,824 floats (x4-divisible)
// path B layout
constexpr int kTPadB   = 768;
constexpr int kBinPadB = 176;
constexpr int kAccB    = kB * kTPadB * kBinPadB * 2;
}

typedef _Float16 half8 __attribute__((ext_vector_type(8)));
typedef _Float16 half2v __attribute__((ext_vector_type(2)));
typedef float floatx4 __attribute__((ext_vector_type(4)));

struct Jobs {          // path B job table (16-bin groups, 2048 slabs)
  int k0[48];
  int lo[48];
  int hi[48];
  int n;
};

struct Jobs4 {         // path A job table (32-bin groups, 512 slabs)
  int k0[kMaxJobs];    // bin-group start (multiple of 32)
  int lo[kMaxJobs];    // slab start col (256-aligned)
  int nch[kMaxJobs];   // 32-col chunks (8 or 16, even)
  int cbase[kMaxJobs]; // chunk prefix sum
  int n;
  int total;
};

__device__ inline void atomAddF(float* p, float v) {
  __hip_atomic_fetch_add(p, v, __ATOMIC_RELAXED, __HIP_MEMORY_SCOPE_AGENT);
}

// ---- fused prep: [0,nbx) padded audio | [nbx,nbx+totch) bpack | rest zero acc
__global__ __launch_bounds__(256) void prep_fused(
    const float* __restrict__ x, const float* __restrict__ kr,
    const float* __restrict__ ki, _Float16* __restrict__ xp,
    _Float16* __restrict__ bp, float* __restrict__ accb,
    const int pad, const int xps, const int nmax,
    const int nbx, const Jobs4 jt) {
  int bid = blockIdx.x;
  const int tid = threadIdx.x;

  if (bid < nbx) {
    // --- padded f16 audio ---
    const int halfx = xps >> 1;
    const int gid = bid * 256 + tid;
    if (gid >= kB * halfx) return;
    const int b = gid / halfx;
    const int i = (gid - b * halfx) * 2;
    float v0 = 0.f, v1 = 0.f;
    if (i     >= pad && i     < pad + kS) v0 = x[(size_t)b * kS + (i - pad)];
    if (i + 1 >= pad && i + 1 < pad + kS) v1 = x[(size_t)b * kS + (i + 1 - pad)];
    half2v h; h.x = (_Float16)v0; h.y = (_Float16)v1;
    *(half2v*)&xp[(size_t)b * xps + i] = h;
    return;
  }
  bid -= nbx;

  if (bid < jt.total) {
    // --- B-fragment pack: one block per chunk; thread -> one 16B fragment ---
    const int chunk = bid;
    int jb = 0;
    #pragma unroll 1
    for (int j = 1; j < jt.n; ++j)
      if (chunk >= jt.cbase[j]) jb = j;
    const int c = chunk - jt.cbase[jb];
    const int region = tid >> 6;          // 0..3: sg0re, sg0im, sg1re, sg1im
    const int l      = tid & 63;          // fragment lane
    const int sg   = region >> 1;
    const int isIm = region & 1;
    const int mm   = l & 15;
    const int q16  = l >> 4;
    const int bin  = jt.k0[jb] + sg * 16 + mm;
    const int col0 = jt.lo[jb] + c * 32 + q16 * 8;
    const float* row = (isIm ? ki : kr) + (size_t)bin * nmax;
    const bool binok = (bin < kBins);
    half8 h;
    #pragma unroll
    for (int j = 0; j < 8; ++j) {
      const int col = col0 + j;
      const bool ok = binok && (col < nmax);
      h[j] = ok ? (_Float16)(row[col] * kKScale) : (_Float16)0.f;
    }
    *(half8*)(bp + (size_t)chunk * 2048 + region * 512 + l * 8) = h;
    return;
  }
  bid -= jt.total;

  // --- zero split-K accumulator ---
  const int idx = (bid * 256 + tid) * 4;
  if (idx < kAccA)
    *(floatx4*)&accb[idx] = (floatx4){0.f, 0.f, 0.f, 0.f};
}

// ---- path A main: 64-frame x 32-bin wave tile, ping-pong prefetch ----
__global__ __launch_bounds__(64, 3) void cqt_mfma4(
    const _Float16* __restrict__ bp, const _Float16* __restrict__ xp,
    float* __restrict__ accb, const int xps, const Jobs4 jt) {
  const int jb = blockIdx.y;
  const int fbk = blockIdx.x >> 2;     // 0..10
  const int b   = blockIdx.x & 3;
  const int lane = threadIdx.x;
  const int m = lane & 15;
  const int q = lane >> 4;
  const int k0 = jt.k0[jb];
  const int lo = jt.lo[jb];
  const int nch = jt.nch[jb];          // even, >= 8
  const int fbase = fbk * 64;

  // per-tile A base pointers, row-clamped to frame 688 (t>=689 is discarded)
  const _Float16* ax[4];
  #pragma unroll
  for (int tl = 0; tl < 4; ++tl) {
    int row = fbase + tl * 16 + m;
    if (row > kT - 1) row = kT - 1;
    ax[tl] = xp + (size_t)b * xps + (size_t)row * kHop + q * 8 + lo;
  }
  const _Float16* bq = bp + (size_t)jt.cbase[jb] * 2048 + lane * 8;

  floatx4 acc[4][2][2];                // [tl][sg][re/im]
  #pragma unroll
  for (int tl = 0; tl < 4; ++tl)
    #pragma unroll
    for (int sg = 0; sg < 2; ++sg)
      #pragma unroll
      for (int ri = 0; ri < 2; ++ri)
        acc[tl][sg][ri] = (floatx4){0.f, 0.f, 0.f, 0.f};

  half8 A0[4], B0[4], A1[4], B1[4];
  auto LOADC = [&](int c, half8* A, half8* B) {
    #pragma unroll
    for (int tl = 0; tl < 4; ++tl)
      A[tl] = *(const half8*)(ax[tl] + c * 32);
    const _Float16* bc = bq + (size_t)c * 2048;
    B[0] = *(const half8*)(bc);
    B[1] = *(const half8*)(bc + 512);
    B[2] = *(const half8*)(bc + 1024);
    B[3] = *(const half8*)(bc + 1536);
  };
  auto STEP = [&](half8* A, half8* B) {
    #pragma unroll
    for (int tl = 0; tl < 4; ++tl) {
      acc[tl][0][0] = __builtin_amdgcn_mfma_f32_16x16x32_f16(A[tl], B[0], acc[tl][0][0], 0, 0, 0);
      acc[tl][0][1] = __builtin_amdgcn_mfma_f32_16x16x32_f16(A[tl], B[1], acc[tl][0][1], 0, 0, 0);
      acc[tl][1][0] = __builtin_amdgcn_mfma_f32_16x16x32_f16(A[tl], B[2], acc[tl][1][0], 0, 0, 0);
      acc[tl][1][1] = __builtin_amdgcn_mfma_f32_16x16x32_f16(A[tl], B[3], acc[tl][1][1], 0, 0, 0);
    }
  };

  LOADC(0, A0, B0);
  int c = 0;
  #pragma unroll 1
  for (; c + 2 < nch; c += 2) {
    LOADC(c + 1, A1, B1);
    STEP(A0, B0);
    LOADC(c + 2, A0, B0);
    STEP(A1, B1);
  }
  LOADC(nch - 1, A1, B1);   // c == nch-2 here
  STEP(A0, B0);
  STEP(A1, B1);

  // epilogue: un-scale + guarded split-K atomic combine
  #pragma unroll
  for (int tl = 0; tl < 4; ++tl) {
    const int tb = fbase + tl * 16 + q * 4;
    #pragma unroll
    for (int sg = 0; sg < 2; ++sg) {
      const int bin = k0 + sg * 16 + m;
      if (bin < kBins) {
        #pragma unroll
        for (int r = 0; r < 4; ++r) {
          const int t = tb + r;
          if (t < kT) {
            const size_t o = (((size_t)b * kT + t) * kBins + bin) * 2;
            atomAddF(&accb[o],     acc[tl][sg][0][r] * kKScaleInv);
            atomAddF(&accb[o + 1], acc[tl][sg][1][r] * kKScaleInv);
          }
        }
      }
    }
  }
}

// ---- final: magnitude (layout-parametric: works for path A and B) ----
__global__ __launch_bounds__(256) void cqt_mag_final(
    const float* __restrict__ accb, float* __restrict__ out,
    const int tp, const int kp) {
  int gid = blockIdx.x * 256 + threadIdx.x;
  if (gid >= kB * kT * kBins) return;
  const int k = gid % kBins;
  const int r = gid / kBins;
  const int t = r % kT;
  const int b = r / kT;
  const float2 v = ((const float2*)accb)[((size_t)b * tp + t) * kp + k];
  out[gid] = sqrtf(v.x * v.x + v.y * v.y);
}

// ================= path B: round-3 LDS-staging MFMA (verified) =============
__global__ __launch_bounds__(256) void prep_x_kernel(
    const float* __restrict__ x, _Float16* __restrict__ xp,
    const int pad, const int xps) {
  const int halfx = xps >> 1;
  int gid = blockIdx.x * 256 + threadIdx.x;
  if (gid >= kB * halfx) return;
  const int b = gid / halfx;
  const int i = (gid - b * halfx) * 2;
  float v0 = 0.f, v1 = 0.f;
  if (i     >= pad && i     < pad + kS) v0 = x[(size_t)b * kS + (i - pad)];
  if (i + 1 >= pad && i + 1 < pad + kS) v1 = x[(size_t)b * kS + (i + 1 - pad)];
  half2v h; h.x = (_Float16)v0; h.y = (_Float16)v1;
  *(half2v*)&xp[(size_t)b * xps + i] = h;
}

__global__ __launch_bounds__(256) void cqt_mfma_kernel(
    const float* __restrict__ kr, const float* __restrict__ ki,
    const _Float16* __restrict__ xp, float* __restrict__ accb,
    const int nmax, const int xps, const Jobs jt) {
  __shared__ _Float16 Bs[2][16][264];
  const int jb = blockIdx.x;
  const int k0   = jt.k0[jb];
  const int n_lo = jt.lo[jb];
  const int n_hi = jt.hi[jb];
  const int b  = blockIdx.z;
  const int fb = blockIdx.y;
  const int tid  = threadIdx.x;
  const int lane = tid & 63;
  const int wave = tid >> 6;
  const int m = lane & 15;
  const int q = lane >> 4;
  const int sbin = tid >> 4;
  const int scol = tid & 15;
  const int gbin = k0 + sbin;
  const bool binok = (gbin < kBins);
  const float* rowr = kr + (size_t)gbin * nmax;
  const float* rowi = ki + (size_t)gbin * nmax;
  const int fbase = fb * 256 + wave * 64;
  const _Float16* ax =
      xp + (size_t)b * xps + (size_t)(fbase + m) * kHop + q * 8;
  floatx4 accr[4], acci[4];
  #pragma unroll
  for (int tl = 0; tl < 4; ++tl) {
    accr[tl] = (floatx4){0.f, 0.f, 0.f, 0.f};
    acci[tl] = (floatx4){0.f, 0.f, 0.f, 0.f};
  }
  for (int n0r = n_lo; n0r < n_hi; n0r += 256) {
    __syncthreads();
    #pragma unroll
    for (int c = 0; c < 16; ++c) {
      const int col = n0r + scol + c * 16;
      const bool ok = binok && (col < nmax);
      const float vr = ok ? rowr[col] : 0.f;
      const float vi = ok ? rowi[col] : 0.f;
      Bs[0][sbin][scol + c * 16] = (_Float16)(vr * kKScale);
      Bs[1][sbin][scol + c * 16] = (_Float16)(vi * kKScale);
    }
    __syncthreads();
    const _Float16* axr = ax + n0r;
    #pragma unroll
    for (int c = 0; c < 8; ++c) {
      const int ko = c * 32 + q * 8;
      const half8 br = *(const half8*)&Bs[0][m][ko];
      const half8 bi = *(const half8*)&Bs[1][m][ko];
      #pragma unroll
      for (int tl = 0; tl < 4; ++tl) {
        const half8 a = *(const half8*)(axr + tl * 16 * kHop + c * 32);
        accr[tl] = __builtin_amdgcn_mfma_f32_16x16x32_f16(a, br, accr[tl], 0, 0, 0);
        acci[tl] = __builtin_amdgcn_mfma_f32_16x16x32_f16(a, bi, acci[tl], 0, 0, 0);
      }
    }
  }
  #pragma unroll
  for (int tl = 0; tl < 4; ++tl) {
    #pragma unroll
    for (int r = 0; r < 4; ++r) {
      const int t = fbase + tl * 16 + q * 4 + r;
      const size_t o = (((size_t)b * kTPadB + t) * kBinPadB + (k0 + m)) * 2;
      atomAddF(&accb[o],     accr[tl][r] * kKScaleInv);
      atomAddF(&accb[o + 1], acci[tl][r] * kKScaleInv);
    }
  }
}

// ================= path C: verified fp32 kernel (round 2) ==================
namespace fb32 {
constexpr int TT = 8;
constexpr int KG = 4;
constexpr int kTTiles  = (kT + TT - 1) / TT;
constexpr int kKGroups = kBins / KG;
constexpr int kWaves   = kB * kTTiles * kKGroups;
}

__global__ __launch_bounds__(256) void cqt_mag_kernel(
    const float* __restrict__ x,
    const float* __restrict__ kr,
    const float* __restrict__ ki,
    float* __restrict__ out,
    const int nmax, const int pad) {
  using namespace fb32;
  const int wave = (blockIdx.x << 2) + (threadIdx.x >> 6);
  const int lane = threadIdx.x & 63;
  if (wave >= kWaves) return;
  const int kg    = wave / (kB * kTTiles);
  const int rem   = wave - kg * (kB * kTTiles);
  const int b     = rem / kTTiles;
  const int ttile = rem - b * kTTiles;
  const int k0 = kg * KG;
  const int t0 = ttile * TT;
  const double Q  = 1.0 / (exp2(1.0 / 24.0) - 1.0);
  const double f0 = 32.7 * exp2((double)k0 / 24.0);
  int N = (int)ceil(Q * (double)kSR / f0) + 8;
  int full_start = nmax - N;
  if (full_start < 0) full_start = 0;
  int tbase[TT], lo[TT], t_last;
  { int t = t0 + TT - 1; if (t > kT - 1) t = kT - 1; t_last = t; }
  #pragma unroll
  for (int tt = 0; tt < TT; ++tt) {
    int t = t0 + tt; if (t > kT - 1) t = kT - 1;
    tbase[tt] = b * kS + t * kHop - pad;
    lo[tt]    = pad - t * kHop;
  }
  int head_start = pad - t_last * kHop;
  if (head_start < full_start) head_start = full_start;
  int safe = pad - t0 * kHop;
  if (safe < head_start) safe = head_start;
  int body_start = nmax - ((nmax - safe) & ~63);
  float accr[TT][KG], acci[TT][KG];
  #pragma unroll
  for (int tt = 0; tt < TT; ++tt)
    #pragma unroll
    for (int kk = 0; kk < KG; ++kk) { accr[tt][kk] = 0.f; acci[tt][kk] = 0.f; }
  for (int n = body_start - 64; n > head_start - 64; n -= 64) {
    const int nn = n + lane;
    const bool kok = (nn >= 0);
    float krv[KG], kiv[KG];
    #pragma unroll
    for (int kk = 0; kk < KG; ++kk) {
      krv[kk] = kok ? kr[(k0 + kk) * nmax + nn] : 0.f;
      kiv[kk] = kok ? ki[(k0 + kk) * nmax + nn] : 0.f;
    }
    float a[TT];
    #pragma unroll
    for (int tt = 0; tt < TT; ++tt)
      a[tt] = (nn >= lo[tt]) ? x[tbase[tt] + nn] : 0.f;
    #pragma unroll
    for (int tt = 0; tt < TT; ++tt)
      #pragma unroll
      for (int kk = 0; kk < KG; ++kk) {
        accr[tt][kk] = fmaf(a[tt], krv[kk], accr[tt][kk]);
        acci[tt][kk] = fmaf(a[tt], kiv[kk], acci[tt][kk]);
      }
  }
  for (int n = body_start; n < nmax; n += 64) {
    const int nn = n + lane;
    float krv[KG], kiv[KG];
    #pragma unroll
    for (int kk = 0; kk < KG; ++kk) {
      krv[kk] = kr[(k0 + kk) * nmax + nn];
      kiv[kk] = ki[(k0 + kk) * nmax + nn];
    }
    float a[TT];
    #pragma unroll
    for (int tt = 0; tt < TT; ++tt)
      a[tt] = x[tbase[tt] + nn];
    #pragma unroll
    for (int tt = 0; tt < TT; ++tt)
      #pragma unroll
      for (int kk = 0; kk < KG; ++kk) {
        accr[tt][kk] = fmaf(a[tt], krv[kk], accr[tt][kk]);
        acci[tt][kk] = fmaf(a[tt], kiv[kk], acci[tt][kk]);
      }
  }
  #pragma unroll
  for (int tt = 0; tt < TT; ++tt) {
    #pragma unroll
    for (int kk = 0; kk < KG; ++kk) {
      float r = accr[tt][kk];
      float i = acci[tt][kk];
      #pragma unroll
      for (int s = 32; s > 0; s >>= 1) {
        r += __shfl_xor(r, s, 64);
        i += __shfl_xor(i, s, 64);
      }
      if (lane == 0) {
        const int t = t0 + tt;
        if (t < kT)
          out[(b * kT + t) * kBins + (k0 + kk)] = sqrtf(r * r + i * i);
      }
    }
  }
}
// ============================================================================

extern "C" void kernel_launch(void* const* d_in, const int* in_sizes, int n_in,
                              void* d_out, int out_size, void* d_ws, size_t ws_size,
                              hipStream_t stream) {
  const float* x  = (const float*)d_in[0];   // [4, 1, 352768]
  const float* kr = (const float*)d_in[1];   // [168, nmax]
  const float* ki = (const float*)d_in[2];   // [168, nmax]
  float* out = (float*)d_out;                // [4, 1, 689, 168]

  const int nmax = in_sizes[1] / kBins;      // 23013 (runtime truth)
  const int pad  = nmax - kHop;

  const int kcap = ((nmax + 255) / 256) * 256;   // 23040
  const double Q = 1.0 / (exp2(1.0 / 24.0) - 1.0);

  // ---- path A layout ----
  const int xpsA = (kT - 1) * kHop + kcap + 256;           // 375,552
  const size_t xpA_bytes = (size_t)kB * xpsA * sizeof(_Float16);
  const size_t accA_off  = (xpA_bytes + 511) & ~(size_t)511;
  const size_t accA_bytes = (size_t)kAccA * sizeof(float);
  const size_t bpA_off   = (accA_off + accA_bytes + 511) & ~(size_t)511;

  // ---- path A job table: 32-bin groups, slab=512, 256-aligned support ----
  Jobs4 j4;
  int nj4 = 0, totch = 0;
  bool ok4 = true;
  for (int g = 0; g < 6; ++g) {
    const int gk0 = 32 * g;
    const double f0 = 32.7 * exp2((double)gk0 / 24.0);
    const int N = (int)ceil(Q * (double)kSR / f0) + 8;
    int lo_r = nmax - N;
    if (lo_r < 0) lo_r = 0;
    lo_r &= ~255;
    for (int s = lo_r; s < kcap; s += 512) {
      if (nj4 >= kMaxJobs) { ok4 = false; break; }
      const int hi = (s + 512 < kcap) ? s + 512 : kcap;
      j4.k0[nj4]    = gk0;
      j4.lo[nj4]    = s;
      j4.nch[nj4]   = (hi - s) / 32;
      j4.cbase[nj4] = totch;
      totch += j4.nch[nj4];
      ++nj4;
    }
    if (!ok4) break;
  }
  j4.n = nj4;        // 77 expected
  j4.total = totch;  // 1216 expected

  const size_t bpA_bytes = (size_t)totch * 4096;
  const size_t ws_A = bpA_off + bpA_bytes;       // ~11.69 MB

  // ---- path B layout ----
  const int xpsB = (kTPadB - 1) * kHop + kcap + 256;       // 416,000
  const size_t xpB_bytes = (size_t)kB * xpsB * sizeof(_Float16);
  const size_t accB_off  = (xpB_bytes + 511) & ~(size_t)511;
  const size_t accB_bytes = (size_t)kAccB * sizeof(float);
  const size_t ws_B = accB_off + accB_bytes;

  if (ok4 && ws_size >= ws_A) {
    // ---- path A ----
    _Float16* xp = (_Float16*)d_ws;
    float* accb  = (float*)((char*)d_ws + accA_off);
    _Float16* bp = (_Float16*)((char*)d_ws + bpA_off);

    const int nbx = (kB * (xpsA / 2) + 255) / 256;   // 2934
    const int nba = (kAccA / 4 + 255) / 256;         // 905
    prep_fused<<<nbx + j4.total + nba, 256, 0, stream>>>(
        x, kr, ki, xp, bp, accb, pad, xpsA, nmax, nbx, j4);

    {
      dim3 grid(44, nj4);   // x = fb(11) * b(4), y = jobs (job-major adjacency)
      cqt_mfma4<<<grid, 64, 0, stream>>>(bp, xp, accb, xpsA, j4);
    }
    {
      const int total = kB * kT * kBins;
      cqt_mag_final<<<(total + 255) / 256, 256, 0, stream>>>(
          accb, out, kT, kBins);
    }
    return;
  }

  if (ws_size >= ws_B) {
    // ---- path B (round-3, verified ~224us) ----
    _Float16* xp = (_Float16*)d_ws;
    float* accb  = (float*)((char*)d_ws + accB_off);
    Jobs jt;
    int nj = 0;
    for (int g = 0; g < 11; ++g) {
      const int gk0 = 16 * g;
      const double f0 = 32.7 * exp2((double)gk0 / 24.0);
      const int N = (int)ceil(Q * (double)kSR / f0) + 8;
      int lo = nmax - N;
      if (lo < 0) lo = 0;
      lo = (lo / 2048) * 2048;
      for (int s = lo; s < kcap && nj < 48; s += 2048) {
        jt.k0[nj] = gk0;
        jt.lo[nj] = s;
        jt.hi[nj] = (s + 2048 < kcap) ? s + 2048 : kcap;
        ++nj;
      }
    }
    jt.n = nj;
    hipMemsetAsync(accb, 0, accB_bytes, stream);
    {
      const int total = kB * (xpsB / 2);
      prep_x_kernel<<<(total + 255) / 256, 256, 0, stream>>>(x, xp, pad, xpsB);
    }
    {
      dim3 grid(nj, kTPadB / 256, kB);
      cqt_mfma_kernel<<<grid, 256, 0, stream>>>(kr, ki, xp, accb, nmax, xpsB, jt);
    }
    {
      const int total = kB * kT * kBins;
      cqt_mag_final<<<(total + 255) / 256, 256, 0, stream>>>(
          accb, out, kTPadB, kBinPadB);
    }
    return;
  }

  // ---- path C: fp32 fallback ----
  {
    const int blocks = fb32::kWaves / 4;
    cqt_mag_kernel<<<blocks, 256, 0, stream>>>(x, kr, ki, out, nmax, pad);
  }
}